// Round 1
// baseline (372.717 us; speedup 1.0000x reference)
//
#include <hip/hip_runtime.h>
#include <math.h>

// Problem constants (fixed by reference):
//   x:     [4, 3, 1024, 1024] f32
//   param: [4, 72, 256, 256]  f32  -> curve[b, c, i*8+z, y, x] with ch = c*24 + i*8 + z
//   out:   [4, 3, 1024, 1024] f32 = tanh(sum_i trilinear(...))
#define IMG_H 1024
#define IMG_W 1024
#define HW (IMG_H * IMG_W)
#define TS 256
#define CH_STRIDE (TS * TS)            // 65536
#define PARAM_B_STRIDE (72 * CH_STRIDE)

__global__ __launch_bounds__(256) void curve3d_kernel(
    const float* __restrict__ x, const float* __restrict__ param,
    float* __restrict__ out)
{
    int idx = blockIdx.x * blockDim.x + threadIdx.x;   // over B*H*W = 4*1024*1024
    int w = idx & (IMG_W - 1);
    int h = (idx >> 10) & (IMG_H - 1);
    int b = idx >> 20;

    // align_corners=True mapping: i = coord_idx * (TS-1)/(IMG-1)
    const float scale = 255.0f / 1023.0f;
    float ix = fminf((float)w * scale, 255.0f);
    float iy = fminf((float)h * scale, 255.0f);
    float x0f = floorf(ix), y0f = floorf(iy);
    float wx = ix - x0f, wy = iy - y0f;
    int x0 = (int)x0f; int x1 = min(x0 + 1, TS - 1);
    int y0 = (int)y0f; int y1 = min(y0 + 1, TS - 1);

    float w00 = (1.0f - wy) * (1.0f - wx);
    float w01 = (1.0f - wy) * wx;
    float w10 = wy * (1.0f - wx);
    float w11 = wy * wx;

    int o00 = y0 * TS + x0, o01 = y0 * TS + x1;
    int o10 = y1 * TS + x0, o11 = y1 * TS + x1;

    const float* pb = param + b * PARAM_B_STRIDE;
    const float* xb = x + (size_t)b * 3 * HW + h * IMG_W + w;

    // z interpolation state per input channel i (border padding, align_corners)
    int z0[3], z1[3];
    float wz[3];
#pragma unroll
    for (int i = 0; i < 3; i++) {
        float xv = xb[i * HW];
        float iz = (xv + 1.0f) * 3.5f;           // (gz+1)*0.5*(D-1), D=8
        iz = fminf(fmaxf(iz, 0.0f), 7.0f);
        float z0f = floorf(iz);
        wz[i] = iz - z0f;
        z0[i] = (int)z0f;
        z1[i] = min(z0[i] + 1, 7);
    }

    float* ob = out + (size_t)b * 3 * HW + h * IMG_W + w;
#pragma unroll
    for (int c = 0; c < 3; c++) {
        float acc = 0.0f;
#pragma unroll
        for (int i = 0; i < 3; i++) {
            const float* p0 = pb + (c * 24 + i * 8 + z0[i]) * CH_STRIDE;
            const float* p1 = pb + (c * 24 + i * 8 + z1[i]) * CH_STRIDE;
            float b0 = w00 * p0[o00] + w01 * p0[o01] + w10 * p0[o10] + w11 * p0[o11];
            float b1 = w00 * p1[o00] + w01 * p1[o01] + w10 * p1[o10] + w11 * p1[o11];
            acc += b0 + wz[i] * (b1 - b0);
        }
        // tanh(acc) = 1 - 2/(exp(2*acc)+1); safe at +-inf
        float e = __expf(2.0f * acc);
        ob[c * HW] = 1.0f - 2.0f / (e + 1.0f);
    }
}

extern "C" void kernel_launch(void* const* d_in, const int* in_sizes, int n_in,
                              void* d_out, int out_size, void* d_ws, size_t ws_size,
                              hipStream_t stream) {
    const float* x = (const float*)d_in[0];
    const float* param = (const float*)d_in[1];
    float* out = (float*)d_out;
    int n_pixels = 4 * HW;   // B*H*W
    dim3 block(256);
    dim3 grid(n_pixels / 256);
    curve3d_kernel<<<grid, block, 0, stream>>>(x, param, out);
}

// Round 2
// 278.041 us; speedup vs baseline: 1.3405x; 1.3405x over previous
//
#include <hip/hip_runtime.h>
#include <math.h>
#include <string.h>

// x:     [4, 3, 1024, 1024] f32
// param: [4, 72, 256, 256]  f32 ; channel = c*24 + i*8 + z = (3c+i)*8 + z
// out:   [4, 3, 1024, 1024] f32 = tanh(sum_i trilinear(curve))
#define IMG_H 1024
#define IMG_W 1024
#define HW (IMG_H * IMG_W)
#define TS 256
#define CH_STRIDE (TS * TS)
#define PARAM_B_STRIDE (72 * CH_STRIDE)
#define TP_B_STRIDE (TS * TS * 72)          // transposed [b][y][x][72]
#define TP_BYTES ((size_t)4 * TP_B_STRIDE * 4)  // 75.5 MB

// ---------- pre-pass: param [b][72][y][x] -> tp [b][y*256+x][72] ----------
__global__ __launch_bounds__(256) void transpose_param(
    const float* __restrict__ param, float* __restrict__ tp)
{
    __shared__ float tile[72][65];   // +1 pad: store-side reads stride 65 -> bank stride 1
    int blk = blockIdx.x;            // b*1024 + y*4 + xt
    int xt = blk & 3;
    int y  = (blk >> 2) & 255;
    int b  = blk >> 10;
    int tid = threadIdx.x;

    const float* src = param + ((b * 72) * TS + y) * TS + xt * 64;
#pragma unroll
    for (int it = 0; it < 18; ++it) {            // 72*64 = 18*256
        int flat = it * 256 + tid;
        int ch = flat >> 6, xx = flat & 63;
        tile[ch][xx] = src[ch * CH_STRIDE + xx]; // coalesced 256B runs
    }
    __syncthreads();
    float* dst = tp + ((size_t)b * TP_B_STRIDE) + ((size_t)(y * TS + xt * 64)) * 72;
#pragma unroll
    for (int it = 0; it < 18; ++it) {            // 64*72 = 18*256
        int flat = it * 256 + tid;
        int xx = flat / 72, ch = flat - xx * 72;
        dst[xx * 72 + ch] = tile[ch][xx];        // coalesced contiguous writes
    }
}

// ---------- main kernel, transposed layout ----------
__global__ __launch_bounds__(256) void curve3d_t_kernel(
    const float* __restrict__ x, const float* __restrict__ tp,
    float* __restrict__ out)
{
    int idx = blockIdx.x * blockDim.x + threadIdx.x;
    int w = idx & (IMG_W - 1);
    int h = (idx >> 10) & (IMG_H - 1);
    int b = idx >> 20;

    const float scale = 255.0f / 1023.0f;
    float ix = fminf((float)w * scale, 255.0f);
    float iy = fminf((float)h * scale, 255.0f);
    float x0f = floorf(ix), y0f = floorf(iy);
    float wx = ix - x0f, wy = iy - y0f;
    int x0 = (int)x0f; int x1 = min(x0 + 1, TS - 1);
    int y0 = (int)y0f; int y1 = min(y0 + 1, TS - 1);

    float w00 = (1.0f - wy) * (1.0f - wx);
    float w01 = (1.0f - wy) * wx;
    float w10 = wy * (1.0f - wx);
    float w11 = wy * wx;

    const float* pb = tp + (size_t)b * TP_B_STRIDE;
    const float* c00 = pb + (y0 * TS + x0) * 72;
    const float* c01 = pb + (y0 * TS + x1) * 72;
    const float* c10 = pb + (y1 * TS + x0) * 72;
    const float* c11 = pb + (y1 * TS + x1) * 72;

    const float* xb = x + (size_t)b * 3 * HW + h * IMG_W + w;
    int zs[3]; float wzs[3];
#pragma unroll
    for (int i = 0; i < 3; i++) {
        float xv = xb[i * HW];
        float iz = fminf(fmaxf((xv + 1.0f) * 3.5f, 0.0f), 7.0f);
        int z = min((int)iz, 6);       // zs in [0,6]; z0==7 -> zs=6, wzs=1
        zs[i] = z;
        wzs[i] = iz - (float)z;
    }

    float* ob = out + (size_t)b * 3 * HW + h * IMG_W + w;
#pragma unroll
    for (int c = 0; c < 3; c++) {
        float acc = 0.0f;
#pragma unroll
        for (int i = 0; i < 3; i++) {
            int off = (c * 3 + i) * 8 + zs[i];
            float2 v00, v01, v10, v11;
            __builtin_memcpy(&v00, c00 + off, 8);
            __builtin_memcpy(&v01, c01 + off, 8);
            __builtin_memcpy(&v10, c10 + off, 8);
            __builtin_memcpy(&v11, c11 + off, 8);
            float wzi = wzs[i];
            float t00 = v00.x + (v00.y - v00.x) * wzi;
            float t01 = v01.x + (v01.y - v01.x) * wzi;
            float t10 = v10.x + (v10.y - v10.x) * wzi;
            float t11 = v11.x + (v11.y - v11.x) * wzi;
            acc += w00 * t00 + w01 * t01 + w10 * t10 + w11 * t11;
        }
        float e = __expf(2.0f * acc);
        ob[c * HW] = 1.0f - 2.0f / (e + 1.0f);
    }
}

// ---------- fallback (original layout) if ws too small ----------
__global__ __launch_bounds__(256) void curve3d_kernel(
    const float* __restrict__ x, const float* __restrict__ param,
    float* __restrict__ out)
{
    int idx = blockIdx.x * blockDim.x + threadIdx.x;
    int w = idx & (IMG_W - 1);
    int h = (idx >> 10) & (IMG_H - 1);
    int b = idx >> 20;

    const float scale = 255.0f / 1023.0f;
    float ix = fminf((float)w * scale, 255.0f);
    float iy = fminf((float)h * scale, 255.0f);
    float x0f = floorf(ix), y0f = floorf(iy);
    float wx = ix - x0f, wy = iy - y0f;
    int x0 = (int)x0f; int x1 = min(x0 + 1, TS - 1);
    int y0 = (int)y0f; int y1 = min(y0 + 1, TS - 1);

    float w00 = (1.0f - wy) * (1.0f - wx);
    float w01 = (1.0f - wy) * wx;
    float w10 = wy * (1.0f - wx);
    float w11 = wy * wx;

    int o00 = y0 * TS + x0, o01 = y0 * TS + x1;
    int o10 = y1 * TS + x0, o11 = y1 * TS + x1;

    const float* pb = param + b * PARAM_B_STRIDE;
    const float* xb = x + (size_t)b * 3 * HW + h * IMG_W + w;

    int z0[3], z1[3];
    float wz[3];
#pragma unroll
    for (int i = 0; i < 3; i++) {
        float xv = xb[i * HW];
        float iz = fminf(fmaxf((xv + 1.0f) * 3.5f, 0.0f), 7.0f);
        float z0f = floorf(iz);
        wz[i] = iz - z0f;
        z0[i] = (int)z0f;
        z1[i] = min(z0[i] + 1, 7);
    }

    float* ob = out + (size_t)b * 3 * HW + h * IMG_W + w;
#pragma unroll
    for (int c = 0; c < 3; c++) {
        float acc = 0.0f;
#pragma unroll
        for (int i = 0; i < 3; i++) {
            const float* p0 = pb + (c * 24 + i * 8 + z0[i]) * CH_STRIDE;
            const float* p1 = pb + (c * 24 + i * 8 + z1[i]) * CH_STRIDE;
            float b0 = w00 * p0[o00] + w01 * p0[o01] + w10 * p0[o10] + w11 * p0[o11];
            float b1 = w00 * p1[o00] + w01 * p1[o01] + w10 * p1[o10] + w11 * p1[o11];
            acc += b0 + wz[i] * (b1 - b0);
        }
        float e = __expf(2.0f * acc);
        ob[c * HW] = 1.0f - 2.0f / (e + 1.0f);
    }
}

extern "C" void kernel_launch(void* const* d_in, const int* in_sizes, int n_in,
                              void* d_out, int out_size, void* d_ws, size_t ws_size,
                              hipStream_t stream) {
    const float* x = (const float*)d_in[0];
    const float* param = (const float*)d_in[1];
    float* out = (float*)d_out;
    int n_pixels = 4 * HW;

    if (ws_size >= TP_BYTES) {
        float* tp = (float*)d_ws;
        transpose_param<<<dim3(4 * TS * 4), dim3(256), 0, stream>>>(param, tp);
        curve3d_t_kernel<<<dim3(n_pixels / 256), dim3(256), 0, stream>>>(x, tp, out);
    } else {
        curve3d_kernel<<<dim3(n_pixels / 256), dim3(256), 0, stream>>>(x, param, out);
    }
}

// Round 3
// 210.344 us; speedup vs baseline: 1.7719x; 1.3218x over previous
//
#include <hip/hip_runtime.h>
#include <math.h>

// x:     [4, 3, 1024, 1024] f32
// param: [4, 72, 256, 256]  f32 ; channel = c*24 + i*8 + z = (3c+i)*8 + z
// out:   [4, 3, 1024, 1024] f32 = tanh(sum_i trilinear(curve))
#define IMG 1024
#define HW (IMG * IMG)
#define TS 256
#define CH_STRIDE (TS * TS)
#define PARAM_B_STRIDE (72 * CH_STRIDE)
#define TP_B_STRIDE (TS * TS * 72)              // transposed [b][y][x][72]
#define TP_BYTES ((size_t)4 * TP_B_STRIDE * 4)  // 75.5 MB
#define S_CONST (255.0f / 1023.0f)

// tile geometry for main kernel
#define TILE_W 64
#define TILE_H 4
#define ROWS 3            // y-span of a 4-row h-tile: <= 3 rows incl. y1
#define CELLS 18          // x-span of a 64-col w-tile: <= 18 cells incl. x1
#define ROW_DW (CELLS * 72)   // 1296 dwords per staged row (5184 B)
#define ROW_F4 (ROW_DW / 4)   // 324 float4 per row

// ---------- pre-pass: param [b][72][y][x] -> tp [b][y*256+x][72] ----------
// float4 on both global sides; LDS tile [64 x][73 ch-pad] breaks conflicts.
__global__ __launch_bounds__(256) void transpose_param(
    const float* __restrict__ param, float* __restrict__ tp)
{
    __shared__ float tile[64 * 73];
    int blk = blockIdx.x;            // b*1024 + y*4 + xt
    int xt = blk & 3;
    int y  = (blk >> 2) & 255;
    int b  = blk >> 10;
    int tid = threadIdx.x;

    const float* srcb = param + (size_t)b * PARAM_B_STRIDE + y * TS + xt * 64;
#pragma unroll
    for (int it = 0; it < 5; ++it) {             // 72 ch * 16 f4 = 1152
        int f = it * 256 + tid;
        if (f < 1152) {
            int ch = f >> 4, q = f & 15;
            float4 v = *(const float4*)(srcb + (size_t)ch * CH_STRIDE + q * 4);
            int xx = q * 4;
            tile[(xx + 0) * 73 + ch] = v.x;
            tile[(xx + 1) * 73 + ch] = v.y;
            tile[(xx + 2) * 73 + ch] = v.z;
            tile[(xx + 3) * 73 + ch] = v.w;
        }
    }
    __syncthreads();
    float4* dst4 = (float4*)(tp + (size_t)b * TP_B_STRIDE + (size_t)(y * TS + xt * 64) * 72);
#pragma unroll
    for (int it = 0; it < 5; ++it) {             // 64 xx * 18 f4 = 1152
        int f = it * 256 + tid;
        if (f < 1152) {
            int xx = f / 18; int j = f - xx * 18; int ch0 = j * 4;
            float4 o;
            o.x = tile[xx * 73 + ch0 + 0];
            o.y = tile[xx * 73 + ch0 + 1];
            o.z = tile[xx * 73 + ch0 + 2];
            o.w = tile[xx * 73 + ch0 + 3];
            dst4[xx * 18 + j] = o;
        }
    }
}

// ---------- main kernel: 64x4 pixel tile, LDS-staged taps ----------
__global__ __launch_bounds__(256) void curve3d_tile(
    const float* __restrict__ x, const float* __restrict__ tp,
    float* __restrict__ out)
{
    __shared__ float lds[ROWS * ROW_DW];   // 15552 B
    int blk = blockIdx.x;                  // b*4096 + ht*16 + wt
    int wt = blk & 15;
    int ht = (blk >> 4) & 255;
    int b  = blk >> 12;
    int tid = threadIdx.x;

    int w0 = wt * TILE_W, h0 = ht * TILE_H;
    int xb = (int)((float)w0 * S_CONST);   // base cell; pixel x0 in [xb, xb+16]
    int yb = (int)((float)h0 * S_CONST);   // base row;  pixel y0 in [yb, yb+1]

    const float* tpb = tp + (size_t)b * TP_B_STRIDE;
#pragma unroll
    for (int r = 0; r < ROWS; ++r) {
        int ysrc = min(yb + r, 255);
        const float4* src = (const float4*)(tpb + (size_t)(ysrc * TS + xb) * 72);
        float4* dst = (float4*)(lds + r * ROW_DW);
#pragma unroll
        for (int it = 0; it < 2; ++it) {   // 324 f4 per row
            int f = it * 256 + tid;
            if (f < ROW_F4) dst[f] = src[f];
        }
    }
    __syncthreads();

    int tw = tid & 63, th = tid >> 6;
    int w = w0 + tw, h = h0 + th;

    float ix = (float)w * S_CONST; int x0 = (int)ix; float wx = ix - (float)x0;
    float iy = (float)h * S_CONST; int y0 = (int)iy; float wy = iy - (float)y0;
    int c0 = x0 - xb;
    int c1 = min(x0 + 1, 255) - xb;
    int r0 = y0 - yb;
    int r1 = min(y0 + 1, 255) - yb;

    const float* base00 = lds + r0 * ROW_DW + c0 * 72;
    const float* base01 = lds + r0 * ROW_DW + c1 * 72;
    const float* base10 = lds + r1 * ROW_DW + c0 * 72;
    const float* base11 = lds + r1 * ROW_DW + c1 * 72;

    const float* xp = x + (size_t)b * 3 * HW + (size_t)h * IMG + w;
    int zi[3]; float wz[3];
#pragma unroll
    for (int i = 0; i < 3; ++i) {
        float xv = xp[(size_t)i * HW];
        float izf = fminf(fmaxf(fmaf(xv, 3.5f, 3.5f), 0.0f), 7.0f);
        int z = min((int)izf, 6);
        zi[i] = z;
        wz[i] = izf - (float)z;
    }

    float u0 = 1.0f - wx, v0 = 1.0f - wy;
    float wc0 = v0 * u0, wc1 = v0 * wx, wc2 = wy * u0, wc3 = wy * wx;
    float wcs[4] = {wc0, wc1, wc2, wc3};
    // premultiplied corner * z weights: wva = wc*(1-wz), wvb = wc*wz
    float wva[4][3], wvb[4][3];
#pragma unroll
    for (int k = 0; k < 4; ++k)
#pragma unroll
        for (int i = 0; i < 3; ++i) {
            wvb[k][i] = wcs[k] * wz[i];
            wva[k][i] = wcs[k] - wvb[k][i];
        }

    const float* bases[4] = {base00, base01, base10, base11};
    float* op = out + (size_t)b * 3 * HW + (size_t)h * IMG + w;
#pragma unroll
    for (int c = 0; c < 3; ++c) {
        float acc = 0.0f;
#pragma unroll
        for (int i = 0; i < 3; ++i) {
            int off = (c * 3 + i) * 8 + zi[i];
#pragma unroll
            for (int k = 0; k < 4; ++k) {
                float2 v;
                __builtin_memcpy(&v, bases[k] + off, 8);   // ds_read2_b32
                acc = fmaf(v.x, wva[k][i], acc);
                acc = fmaf(v.y, wvb[k][i], acc);
            }
        }
        float e = __expf(2.0f * acc);
        op[(size_t)c * HW] = 1.0f - 2.0f / (e + 1.0f);
    }
}

// ---------- fallback (original layout) if ws too small ----------
__global__ __launch_bounds__(256) void curve3d_kernel(
    const float* __restrict__ x, const float* __restrict__ param,
    float* __restrict__ out)
{
    int idx = blockIdx.x * blockDim.x + threadIdx.x;
    int w = idx & (IMG - 1);
    int h = (idx >> 10) & (IMG - 1);
    int b = idx >> 20;

    float ix = fminf((float)w * S_CONST, 255.0f);
    float iy = fminf((float)h * S_CONST, 255.0f);
    float x0f = floorf(ix), y0f = floorf(iy);
    float wx = ix - x0f, wy = iy - y0f;
    int x0 = (int)x0f; int x1 = min(x0 + 1, TS - 1);
    int y0 = (int)y0f; int y1 = min(y0 + 1, TS - 1);

    float w00 = (1.0f - wy) * (1.0f - wx);
    float w01 = (1.0f - wy) * wx;
    float w10 = wy * (1.0f - wx);
    float w11 = wy * wx;

    int o00 = y0 * TS + x0, o01 = y0 * TS + x1;
    int o10 = y1 * TS + x0, o11 = y1 * TS + x1;

    const float* pb = param + b * PARAM_B_STRIDE;
    const float* xb = x + (size_t)b * 3 * HW + h * IMG + w;

    int z0[3], z1[3];
    float wz[3];
#pragma unroll
    for (int i = 0; i < 3; i++) {
        float xv = xb[i * HW];
        float iz = fminf(fmaxf((xv + 1.0f) * 3.5f, 0.0f), 7.0f);
        float z0f = floorf(iz);
        wz[i] = iz - z0f;
        z0[i] = (int)z0f;
        z1[i] = min(z0[i] + 1, 7);
    }

    float* ob = out + (size_t)b * 3 * HW + h * IMG + w;
#pragma unroll
    for (int c = 0; c < 3; c++) {
        float acc = 0.0f;
#pragma unroll
        for (int i = 0; i < 3; i++) {
            const float* p0 = pb + (c * 24 + i * 8 + z0[i]) * CH_STRIDE;
            const float* p1 = pb + (c * 24 + i * 8 + z1[i]) * CH_STRIDE;
            float b0 = w00 * p0[o00] + w01 * p0[o01] + w10 * p0[o10] + w11 * p0[o11];
            float b1 = w00 * p1[o00] + w01 * p1[o01] + w10 * p1[o10] + w11 * p1[o11];
            acc += b0 + wz[i] * (b1 - b0);
        }
        float e = __expf(2.0f * acc);
        ob[c * HW] = 1.0f - 2.0f / (e + 1.0f);
    }
}

extern "C" void kernel_launch(void* const* d_in, const int* in_sizes, int n_in,
                              void* d_out, int out_size, void* d_ws, size_t ws_size,
                              hipStream_t stream) {
    const float* x = (const float*)d_in[0];
    const float* param = (const float*)d_in[1];
    float* out = (float*)d_out;

    if (ws_size >= TP_BYTES) {
        float* tp = (float*)d_ws;
        transpose_param<<<dim3(4 * TS * 4), dim3(256), 0, stream>>>(param, tp);
        // blocks: 16 w-tiles * 256 h-tiles * 4 batches
        curve3d_tile<<<dim3(16 * 256 * 4), dim3(256), 0, stream>>>(x, tp, out);
    } else {
        curve3d_kernel<<<dim3(4 * HW / 256), dim3(256), 0, stream>>>(x, param, out);
    }
}